// Round 3
// baseline (284.482 us; speedup 1.0000x reference)
//
#include <hip/hip_runtime.h>

// 3x3 VALID conv, NCHW fp32: data [16,64,128,128], weights [128,64,3,3]
// -> out [16,128,126,126].
// v3: barrier-free K-loop.
//   - NHWC-bf16 pre-transpose (t1) + weight repack [tap][co][ci] bf16 (t2)
//   - conv: halo (10h x 34w x 64ci, CPAD=72 shorts -> 144B pixel stride)
//     staged ONCE per block; single __syncthreads; then 9 taps x 64 MFMA
//     with A-fragments read straight from global (weights = 144KB, L2-hot).
//   - block tile 128co x 256 spatial (8h x 32w), 4 waves, acc[4][8] f32x4.

#define BATCH 16
#define CIN   64
#define HIN   128
#define WIN   128
#define COUT  128
#define HO    126
#define WO    126

#define HROW 10
#define HPIX 34
#define CPAD 72   // shorts per halo pixel; 144B stride, keeps b128 16B-aligned

typedef short bf16x8 __attribute__((ext_vector_type(8)));
typedef float f32x4  __attribute__((ext_vector_type(4)));
typedef unsigned short u16x8 __attribute__((ext_vector_type(8)));

__device__ __forceinline__ unsigned short f2bf(float f) {
    union { float f; unsigned int u; } v; v.f = f;
    unsigned int u = v.u;
    return (unsigned short)((u + 0x7fffu + ((u >> 16) & 1u)) >> 16);
}

// ---------- Pre-pass 1: NCHW fp32 -> NHWC bf16 ----------
// grid (128 h, 16 b), block 256. Block handles one (b,h): 64ci x 128w.
__global__ __launch_bounds__(256) void t1_nchw_to_nhwc(
        const float* __restrict__ x, unsigned short* __restrict__ y) {
    __shared__ unsigned short tile[64 * 132]; // [ci][w], row 132 shorts
    const int h = blockIdx.x, b = blockIdx.y;
    const int t = threadIdx.x;

    const float* src = x + ((size_t)b * CIN) * (HIN * WIN) + h * WIN;
#pragma unroll
    for (int i = 0; i < 8; i++) {
        const int idx = t + i * 256;
        const int ci = idx >> 5, w4 = (idx & 31) * 4;
        float4 v = *(const float4*)(src + (size_t)ci * (HIN * WIN) + w4);
        ushort4 u = { f2bf(v.x), f2bf(v.y), f2bf(v.z), f2bf(v.w) };
        *(ushort4*)&tile[ci * 132 + w4] = u;
    }
    __syncthreads();

    unsigned short* dst = y + (((size_t)b * HIN + h) * WIN) * CIN;
#pragma unroll
    for (int i = 0; i < 4; i++) {
        const int idx = t + i * 256;
        const int w = idx >> 3, c8 = (idx & 7) * 8;
        u16x8 u;
#pragma unroll
        for (int j = 0; j < 8; j++)
            u[j] = tile[(c8 + j) * 132 + w];
        *(u16x8*)&dst[(size_t)w * CIN + c8] = u;
    }
}

// ---------- Pre-pass 2: weights [co][ci][3][3] fp32 -> [tap][co][ci] bf16 ----------
__global__ __launch_bounds__(256) void t2_weights(
        const float* __restrict__ w, unsigned short* __restrict__ wt) {
    const int idx = blockIdx.x * 256 + threadIdx.x;
    if (idx < COUT * CIN * 9) {
        const int co = idx / (CIN * 9);
        const int r  = idx % (CIN * 9);
        const int ci = r / 9;
        const int k  = r % 9;
        wt[((size_t)k * COUT + co) * CIN + ci] = f2bf(w[idx]);
    }
}

// ---------- Main: barrier-free implicit-GEMM MFMA conv ----------
// grid (4 wtiles, 16 htiles, 16 b) = 1024 blocks, 256 threads (4 waves).
// Block tile: 128co x (8h x 32w). K = 9 taps x 64 ci. A from global (L2).
__global__ __launch_bounds__(256, 2) void conv_mfma(
        const unsigned short* __restrict__ nhwc,   // [b][h][w][ci] bf16
        const unsigned short* __restrict__ wt,     // [tap][co][ci] bf16
        float* __restrict__ out) {
    __shared__ short Hs[HROW * HPIX * CPAD];  // 48960 B halo

    const int w0 = blockIdx.x * 32;
    const int h0 = blockIdx.y * 8;
    const int b  = blockIdx.z;
    const int tid = threadIdx.x;
    const int lane = tid & 63, wave = tid >> 6;
    const int wm = wave & 1, wn = wave >> 1;
    const int col = lane & 15, quad = lane >> 4;

    // ---- stage halo: 10 rows x 34 pixels x 128B = 2720 16B-chunks
    {
        const unsigned short* base = nhwc + ((size_t)b * HIN) * (WIN * CIN);
#pragma unroll
        for (int i = 0; i < 11; i++) {
            const int idx = tid + i * 256;
            if (idx < HROW * HPIX * 8) {
                const int c = idx & 7;
                const int pixel = idx >> 3;
                const int r = pixel / HPIX;
                const int p = pixel - r * HPIX;
                int h = h0 + r; if (h > HIN - 1) h = HIN - 1; // clamp (masked outs)
                bf16x8 v = *(const bf16x8*)(base + ((size_t)h * WIN + w0 + p) * CIN + c * 8);
                *(bf16x8*)&Hs[(r * HPIX + p) * CPAD + c * 8] = v;
            }
        }
    }
    __syncthreads(); // the ONLY barrier

    // B-fragment LDS offsets (shorts)
    int boff[8];
#pragma unroll
    for (int ni = 0; ni < 8; ni++) {
        const int dy = wn * 4 + (ni >> 1);
        const int dx = (ni & 1) * 16 + col;
        boff[ni] = (dy * HPIX + dx) * CPAD + quad * 8;
    }
    // A-fragment global base (shorts into wt): + t*8192 + mi*16*64 + kk*32
    const int agoff = (wm * 64 + col) * CIN + quad * 8;

    f32x4 acc[4][8] = {};

#pragma unroll
    for (int t = 0; t < 9; t++) {
        const int kh = t / 3, kw = t % 3;
        const int hshift = (kh * HPIX + kw) * CPAD;
        const unsigned short* wtap = wt + (size_t)t * (COUT * CIN);

#pragma unroll
        for (int kk = 0; kk < 2; kk++) {
            const int k0 = kk * 32;
            bf16x8 a[4], bb[8];
#pragma unroll
            for (int mi = 0; mi < 4; mi++)
                a[mi] = *(const bf16x8*)(wtap + agoff + mi * 16 * CIN + k0);
#pragma unroll
            for (int ni = 0; ni < 8; ni++)
                bb[ni] = *(const bf16x8*)&Hs[boff[ni] + hshift + k0];
#pragma unroll
            for (int mi = 0; mi < 4; mi++)
#pragma unroll
                for (int ni = 0; ni < 8; ni++)
                    acc[mi][ni] = __builtin_amdgcn_mfma_f32_16x16x32_bf16(
                        a[mi], bb[ni], acc[mi][ni], 0, 0, 0);
        }
    }

    // ---- epilogue. C/D: col(spatial)=lane&15, row(co)=quad*4+reg.
    // Pair the two 16-w halves per (co,oh) so 64B+64B stores merge to 128B lines.
    const int ow0 = w0 + col;            // always < WO (max 111)
    const bool ok1 = (ow0 + 16) < WO;    // only edge tile masks
#pragma unroll
    for (int jj = 0; jj < 4; jj++) {
        const int oh = h0 + wn * 4 + jj;
        if (oh < HO) {
#pragma unroll
            for (int mi = 0; mi < 4; mi++) {
                const int co = wm * 64 + mi * 16 + quad * 4;
                float* o = out + (((size_t)b * COUT + co) * HO + oh) * WO + ow0;
#pragma unroll
                for (int r = 0; r < 4; r++) {
                    o[(size_t)r * HO * WO] = acc[mi][2 * jj][r];
                    if (ok1) o[(size_t)r * HO * WO + 16] = acc[mi][2 * jj + 1][r];
                }
            }
        }
    }
}

// ---------- Fallback: direct fp32 conv (if d_ws too small) ----------
__global__ __launch_bounds__(256) void conv_direct(
        const float* __restrict__ x, const float* __restrict__ w,
        float* __restrict__ y) {
    const int idx = blockIdx.x * 256 + threadIdx.x;
    if (idx >= BATCH * COUT * HO * WO) return;
    const int ow = idx % WO;
    int t = idx / WO;
    const int oh = t % HO; t /= HO;
    const int co = t % COUT;
    const int b  = t / COUT;
    float acc = 0.f;
    const float* xb = x + (((size_t)b * CIN) * HIN + oh) * WIN + ow;
    const float* wc = w + (size_t)co * (CIN * 9);
    for (int ci = 0; ci < CIN; ci++) {
#pragma unroll
        for (int kh = 0; kh < 3; kh++)
#pragma unroll
            for (int kw = 0; kw < 3; kw++)
                acc += xb[(size_t)ci * (HIN * WIN) + kh * WIN + kw] * wc[ci * 9 + kh * 3 + kw];
    }
    y[idx] = acc;
}

extern "C" void kernel_launch(void* const* d_in, const int* in_sizes, int n_in,
                              void* d_out, int out_size, void* d_ws, size_t ws_size,
                              hipStream_t stream) {
    const float* data    = (const float*)d_in[0];
    const float* weights = (const float*)d_in[1];
    float* out = (float*)d_out;

    const size_t nhwc_bytes = (size_t)BATCH * HIN * WIN * CIN * 2; // 32 MiB
    const size_t slack = 4096;                                     // halo overflow pad
    const size_t wt_bytes = (size_t)9 * COUT * CIN * 2;            // 144 KiB
    const size_t need = nhwc_bytes + slack + wt_bytes;

    if (ws_size >= need) {
        unsigned short* nhwc = (unsigned short*)d_ws;
        unsigned short* wt   = (unsigned short*)((char*)d_ws + nhwc_bytes + slack);
        t1_nchw_to_nhwc<<<dim3(HIN, BATCH), 256, 0, stream>>>(data, nhwc);
        t2_weights<<<(COUT * CIN * 9 + 255) / 256, 256, 0, stream>>>(weights, wt);
        conv_mfma<<<dim3(4, 16, BATCH), 256, 0, stream>>>(nhwc, wt, out);
    } else {
        const int n = BATCH * COUT * HO * WO;
        conv_direct<<<(n + 255) / 256, 256, 0, stream>>>(data, weights, out);
    }
}